// Round 5
// baseline (360.957 us; speedup 1.0000x reference)
//
#include <hip/hip_runtime.h>
#include <math.h>

#define N      6144
#define NFEAT  128
#define HID    128
#define NHEADS 8
#define NCLASS 40
#define CAP    96        // ELL capacity per row; mean degree ~13
#define EPS    1e-5f
#define ALPHA  0.2f

typedef short bf16x8 __attribute__((ext_vector_type(8)));
typedef float f32x4  __attribute__((ext_vector_type(4)));

__device__ inline float bf2f(unsigned short u) {
  unsigned int x = ((unsigned int)u) << 16;
  return __builtin_bit_cast(float, x);
}
__device__ inline unsigned short f2bf(float f) {
  unsigned int x = __builtin_bit_cast(unsigned int, f);
  x += 0x7fffu + ((x >> 16) & 1u);          // round-to-nearest-even
  return (unsigned short)(x >> 16);
}

// ------- fused: ELL build (blocks 0..N-1) + BN0/W prep (blocks N..) -------
__global__ __launch_bounds__(256) void prep_ell_kernel(
    const float* __restrict__ adj,
    int* __restrict__ cols, float* __restrict__ vals, int* __restrict__ cnt,
    const float* __restrict__ x,
    const float* __restrict__ g, const float* __restrict__ b,
    const float* __restrict__ m, const float* __restrict__ v,
    const float* __restrict__ Wall,
    unsigned short* __restrict__ xb, unsigned short* __restrict__ wbt) {
  __shared__ int scnt;
  if (blockIdx.x < N) {
    const int i = blockIdx.x;
    if (threadIdx.x == 0) scnt = 0;
    __syncthreads();
    const float* row = adj + (size_t)i * N;
    for (int j4 = threadIdx.x * 4; j4 < N; j4 += 1024) {
      float4 a = *(const float4*)(row + j4);
#pragma unroll
      for (int u = 0; u < 4; ++u) {
        float av = (u == 0) ? a.x : (u == 1) ? a.y : (u == 2) ? a.z : a.w;
        if (av > 0.f) {
          int s = atomicAdd(&scnt, 1);
          if (s < CAP) {
            cols[(size_t)i * CAP + s] = j4 + u;
            vals[(size_t)i * CAP + s] = av;
          }
        }
      }
    }
    __syncthreads();
    if (threadIdx.x == 0) cnt[i] = min(scnt, CAP);
  } else {
    int idx = (blockIdx.x - N) * 256 + threadIdx.x;
    if (idx < N * NFEAT) {
      int c = idx & (NFEAT - 1);
      float sc = g[c] * rsqrtf(v[c] + EPS);
      xb[idx] = f2bf((x[idx] - m[c]) * sc + b[c]);
    } else {
      int t = idx - N * NFEAT;            // t indexes wbt [h][n][k]
      int h = t >> 14, nk = t & 16383, n = nk >> 7, k = nk & 127;
      wbt[t] = f2bf(Wall[(h << 14) + (k << 7) + n]);
    }
  }
}

// ------- GEMM (bf16 MFMA, LDS-staged) + fused score epilogue --------------
__global__ __launch_bounds__(256) void gemm_score(
    const unsigned short* __restrict__ xb,   // [N][128] bf16
    const unsigned short* __restrict__ wbt,  // [h][n][k] bf16 (W^T per head)
    const float* __restrict__ a_src, const float* __restrict__ a_dst,
    unsigned short* __restrict__ whc,        // [N][NHEADS*HID] bf16
    float* __restrict__ s1, float* __restrict__ s2) {
  const int h  = blockIdx.y;
  const int rb = blockIdx.x * 64;
  __shared__ unsigned short As[64][136];     // +8 pad: 16B-aligned, 2-way free
  __shared__ unsigned short Bs[128][136];
  __shared__ float s1p[64], s2p[64];
  const int tid = threadIdx.x;

  if (tid < 64) { s1p[tid] = 0.f; s2p[tid] = 0.f; }
#pragma unroll
  for (int r = 0; r < 4; ++r) {              // stage A: 64x128, coalesced
    int chunk = tid + r * 256;
    int row = chunk >> 4, c8 = (chunk & 15) * 8;
    *(uint4*)&As[row][c8] = *(const uint4*)(xb + (size_t)(rb + row) * NFEAT + c8);
  }
  const unsigned short* W = wbt + h * (HID * NFEAT);
#pragma unroll
  for (int r = 0; r < 8; ++r) {              // stage B: 128x128, coalesced
    int chunk = tid + r * 256;
    int row = chunk >> 4, c8 = (chunk & 15) * 8;
    *(uint4*)&Bs[row][c8] = *(const uint4*)(W + (size_t)row * NFEAT + c8);
  }
  __syncthreads();

  const int wid = tid >> 6, l = tid & 63, lm = l & 15, lq = l >> 4;
  const int cw = wid * 32;
  f32x4 acc[4][2] = {};
#pragma unroll
  for (int kk = 0; kk < NFEAT; kk += 32) {
    bf16x8 af[4], bfr[2];
#pragma unroll
    for (int mt = 0; mt < 4; ++mt)
      af[mt] = *(const bf16x8*)&As[mt * 16 + lm][kk + lq * 8];
#pragma unroll
    for (int nt = 0; nt < 2; ++nt)
      bfr[nt] = *(const bf16x8*)&Bs[cw + nt * 16 + lm][kk + lq * 8];
#pragma unroll
    for (int mt = 0; mt < 4; ++mt)
#pragma unroll
      for (int nt = 0; nt < 2; ++nt)
        acc[mt][nt] = __builtin_amdgcn_mfma_f32_16x16x32_bf16(
            af[mt], bfr[nt], acc[mt][nt], 0, 0, 0);
  }

  unsigned short* C = whc + (size_t)h * HID;
#pragma unroll
  for (int mt = 0; mt < 4; ++mt)
#pragma unroll
    for (int nt = 0; nt < 2; ++nt)
#pragma unroll
      for (int r = 0; r < 4; ++r)
        C[(size_t)(rb + mt * 16 + lq * 4 + r) * (NHEADS * HID)
          + cw + nt * 16 + lm] = f2bf(acc[mt][nt][r]);

  const float as0 = a_src[h * HID + cw + lm];
  const float as1 = a_src[h * HID + cw + 16 + lm];
  const float ad0 = a_dst[h * HID + cw + lm];
  const float ad1 = a_dst[h * HID + cw + 16 + lm];
#pragma unroll
  for (int mt = 0; mt < 4; ++mt)
#pragma unroll
    for (int r = 0; r < 4; ++r) {
      float p1 = acc[mt][0][r] * as0 + acc[mt][1][r] * as1;
      float p2 = acc[mt][0][r] * ad0 + acc[mt][1][r] * ad1;
#pragma unroll
      for (int off = 1; off < 16; off <<= 1) {
        p1 += __shfl_xor(p1, off, 64);
        p2 += __shfl_xor(p2, off, 64);
      }
      if (lm == 0) {
        atomicAdd(&s1p[mt * 16 + lq * 4 + r], p1);
        atomicAdd(&s2p[mt * 16 + lq * 4 + r], p2);
      }
    }
  __syncthreads();
  if (tid < 64) {
    s1[(size_t)h * N + rb + tid] = s1p[tid];
    s2[(size_t)h * N + rb + tid] = s2p[tid];
  }
}

// ------- attention: one block per row, all 8 heads ------------------------
// Phase 1: 16 thr/head softmax. Phase 2: edge-pair split — thread t covers
// features 8q..8q+7 (q=t&127) of edge e+(t>>7) via one uint4 load; parity
// partials merged in LDS (stride-9 pad: conflict-free), BN1+ReLU epilogue.
__global__ __launch_bounds__(256) void attn_kernel(
    const unsigned short* __restrict__ whc,  // [N][1024]
    const float* __restrict__ s1, const float* __restrict__ s2,
    const int* __restrict__ cols, const int* __restrict__ cnt,
    const float* __restrict__ g, const float* __restrict__ b,
    const float* __restrict__ m, const float* __restrict__ v,
    float* __restrict__ xcat) {
  const int i = blockIdx.x, t = threadIdx.x;
  __shared__ int   jsh[CAP + 2];
  __shared__ float wsh[NHEADS][CAP + 2];
  __shared__ float ssum[NHEADS];
  __shared__ float accsh[128][9];

  const int c = cnt[i];
  const int cpad = (c + 1) & ~1;
  if (t < CAP + 2) jsh[t] = (t < c) ? cols[(size_t)i * CAP + t] : 0;
  if (t < 16) wsh[t >> 1][c + (t & 1)] = 0.f;    // zero 2-pad for all heads
  __syncthreads();

  if (t < 128) {                       // 16 threads per head
    const int h = t >> 4, u = t & 15;
    const float si = s1[(size_t)h * N + i];
    const float* s2h = s2 + (size_t)h * N;
    float mx = -INFINITY;
    for (int e = u; e < c; e += 16) {
      float val = si + s2h[jsh[e]];
      val = val >= 0.f ? val : ALPHA * val;
      mx = fmaxf(mx, val);
    }
#pragma unroll
    for (int off = 1; off < 16; off <<= 1) mx = fmaxf(mx, __shfl_xor(mx, off, 64));
    float sm = 0.f;
    for (int e = u; e < c; e += 16) {
      float val = si + s2h[jsh[e]];
      val = val >= 0.f ? val : ALPHA * val;
      float wv = expf(val - mx);
      wsh[h][e] = wv;
      sm += wv;
    }
#pragma unroll
    for (int off = 1; off < 16; off <<= 1) sm += __shfl_xor(sm, off, 64);
    if (u == 0) ssum[h] = sm;
  }
  __syncthreads();

  const int p  = t >> 7;               // edge parity
  const int q  = t & 127;              // feature block: feats 8q..8q+7
  const int f0 = q * 8;
  const int hh = q >> 4;               // head of this feature block
  float acc[8] = {0.f, 0.f, 0.f, 0.f, 0.f, 0.f, 0.f, 0.f};
  for (int e = 0; e < cpad; e += 2) {
    const int   j = jsh[e + p];
    const float w = wsh[hh][e + p];
    uint4 U = *(const uint4*)(whc + (size_t)j * (NHEADS * HID) + f0);
    acc[0] += w * bf2f((unsigned short)(U.x & 0xffff));
    acc[1] += w * bf2f((unsigned short)(U.x >> 16));
    acc[2] += w * bf2f((unsigned short)(U.y & 0xffff));
    acc[3] += w * bf2f((unsigned short)(U.y >> 16));
    acc[4] += w * bf2f((unsigned short)(U.z & 0xffff));
    acc[5] += w * bf2f((unsigned short)(U.z >> 16));
    acc[6] += w * bf2f((unsigned short)(U.w & 0xffff));
    acc[7] += w * bf2f((unsigned short)(U.w >> 16));
  }
  if (p == 1) {
#pragma unroll
    for (int j = 0; j < 8; ++j) accsh[q][j] = acc[j];
  }
  __syncthreads();
  if (p == 0) {
    const float inv = 1.f / ssum[hh];
    const int ch0 = (q & 15) * 8;      // BN channel base within head
    float4 gv0 = *(const float4*)(g + ch0), gv1 = *(const float4*)(g + ch0 + 4);
    float4 bv0 = *(const float4*)(b + ch0), bv1 = *(const float4*)(b + ch0 + 4);
    float4 mv0 = *(const float4*)(m + ch0), mv1 = *(const float4*)(m + ch0 + 4);
    float4 vv0 = *(const float4*)(v + ch0), vv1 = *(const float4*)(v + ch0 + 4);
    float gg[8] = {gv0.x, gv0.y, gv0.z, gv0.w, gv1.x, gv1.y, gv1.z, gv1.w};
    float bb[8] = {bv0.x, bv0.y, bv0.z, bv0.w, bv1.x, bv1.y, bv1.z, bv1.w};
    float mm[8] = {mv0.x, mv0.y, mv0.z, mv0.w, mv1.x, mv1.y, mv1.z, mv1.w};
    float vv[8] = {vv0.x, vv0.y, vv0.z, vv0.w, vv1.x, vv1.y, vv1.z, vv1.w};
    float o[8];
#pragma unroll
    for (int j = 0; j < 8; ++j) {
      float hp = (acc[j] + accsh[q][j]) * inv;
      o[j] = fmaxf((hp - mm[j]) * (gg[j] * rsqrtf(vv[j] + EPS)) + bb[j], 0.f);
    }
    float* xr = xcat + (size_t)i * (NHEADS * HID) + f0;
    float4 o0 = {o[0], o[1], o[2], o[3]}, o1 = {o[4], o[5], o[6], o[7]};
    *(float4*)xr = o0;
    *(float4*)(xr + 4) = o1;
  }
}

// ---------------- support = xcat @ gc_w; wave = 2 rows, lane = class -----
__global__ __launch_bounds__(256) void support_kernel(
    const float* __restrict__ xcat, const float* __restrict__ gcw,
    float* __restrict__ sup) {
  int wave = (blockIdx.x * 256 + threadIdx.x) >> 6;   // 0..3071
  int lane = threadIdx.x & 63;
  int cc = lane < NCLASS ? lane : NCLASS - 1;
  const float* x0 = xcat + (size_t)(wave * 2 + 0) * (NHEADS * HID);
  const float* x1 = xcat + (size_t)(wave * 2 + 1) * (NHEADS * HID);
  float a0 = 0.f, a1 = 0.f;
#pragma unroll 4
  for (int k = 0; k < NHEADS * HID; k += 4) {
    float4 v0 = *(const float4*)(x0 + k);          // broadcast
    float4 v1 = *(const float4*)(x1 + k);
    float w0 = gcw[(size_t)(k + 0) * NCLASS + cc];
    float w1 = gcw[(size_t)(k + 1) * NCLASS + cc];
    float w2 = gcw[(size_t)(k + 2) * NCLASS + cc];
    float w3 = gcw[(size_t)(k + 3) * NCLASS + cc];
    a0 += v0.x * w0 + v0.y * w1 + v0.z * w2 + v0.w * w3;
    a1 += v1.x * w0 + v1.y * w1 + v1.z * w2 + v1.w * w3;
  }
  if (lane < NCLASS) {
    sup[(size_t)(wave * 2 + 0) * NCLASS + lane] = a0;
    sup[(size_t)(wave * 2 + 1) * NCLASS + lane] = a1;
  }
}

// --------- out = log_softmax((0.5*A@sup + sup)/1.5 + gc_b), wave per row -
__global__ __launch_bounds__(64) void final_kernel(
    const float* __restrict__ sup,
    const int* __restrict__ cols, const float* __restrict__ vals,
    const int* __restrict__ cnt, const float* __restrict__ gcb,
    float* __restrict__ out) {
  const int i = blockIdx.x, t = threadIdx.x;
  const bool act = t < NCLASS;
  const int c = cnt[i];
  const int* cl = cols + (size_t)i * CAP;
  const float* vl = vals + (size_t)i * CAP;
  float s = act ? sup[(size_t)i * NCLASS + t] : 0.f;
  float agg = 0.f;
  for (int e = 0; e < c; ++e) {
    int j = cl[e];
    float a = vl[e];
    if (act) agg += a * sup[(size_t)j * NCLASS + t];
  }
  float o = act ? ((0.5f * agg + s) * (1.f / 1.5f) + gcb[t]) : -INFINITY;
  float mx = o;
#pragma unroll
  for (int off = 32; off; off >>= 1) mx = fmaxf(mx, __shfl_xor(mx, off, 64));
  float ex = act ? expf(o - mx) : 0.f;
#pragma unroll
  for (int off = 32; off; off >>= 1) ex += __shfl_xor(ex, off, 64);
  if (act) out[(size_t)i * NCLASS + t] = o - mx - logf(ex);
}

// -------------------------------------------------------------------------
extern "C" void kernel_launch(void* const* d_in, const int* in_sizes, int n_in,
                              void* d_out, int out_size, void* d_ws, size_t ws_size,
                              hipStream_t stream) {
  const float* x     = (const float*)d_in[0];
  const float* adj   = (const float*)d_in[1];
  const float* W_att = (const float*)d_in[2];
  const float* a_src = (const float*)d_in[3];
  const float* a_dst = (const float*)d_in[4];
  const float* bn0_g = (const float*)d_in[5];
  const float* bn0_b = (const float*)d_in[6];
  const float* bn0_m = (const float*)d_in[7];
  const float* bn0_v = (const float*)d_in[8];
  const float* bn1_g = (const float*)d_in[9];
  const float* bn1_b = (const float*)d_in[10];
  const float* bn1_m = (const float*)d_in[11];
  const float* bn1_v = (const float*)d_in[12];
  const float* gc_w  = (const float*)d_in[13];
  const float* gc_b  = (const float*)d_in[14];
  float* out = (float*)d_out;
  (void)in_sizes; (void)n_in; (void)out_size; (void)ws_size;

  char* w = (char*)d_ws;
  unsigned short* xb  = (unsigned short*)w; w += (size_t)N * NFEAT * 2;
  unsigned short* wbt = (unsigned short*)w; w += (size_t)NHEADS * NFEAT * HID * 2;
  unsigned short* whc = (unsigned short*)w; w += (size_t)N * NHEADS * HID * 2;
  float* s1   = (float*)w; w += (size_t)NHEADS * N * 4;
  float* s2   = (float*)w; w += (size_t)NHEADS * N * 4;
  float* xcat = (float*)w; w += (size_t)N * NHEADS * HID * 4;
  float* sup  = (float*)w; w += (size_t)N * NCLASS * 4;
  float* vals = (float*)w; w += (size_t)N * CAP * 4;
  int*   cols = (int*)w;   w += (size_t)N * CAP * 4;
  int*   cnt  = (int*)w;   w += (size_t)N * 4;

  const int prep_blocks = (N * NFEAT + NHEADS * NFEAT * HID) / 256;  // 3584
  prep_ell_kernel<<<dim3(N + prep_blocks), dim3(256), 0, stream>>>(
      adj, cols, vals, cnt, x, bn0_g, bn0_b, bn0_m, bn0_v, W_att, xb, wbt);
  gemm_score<<<dim3(N / 64, NHEADS), dim3(256), 0, stream>>>(
      xb, wbt, a_src, a_dst, whc, s1, s2);
  attn_kernel<<<dim3(N), dim3(256), 0, stream>>>(
      whc, s1, s2, cols, cnt, bn1_g, bn1_b, bn1_m, bn1_v, xcat);
  support_kernel<<<dim3((N / 2) * 64 / 256), dim3(256), 0, stream>>>(
      xcat, gc_w, sup);
  final_kernel<<<dim3(N), dim3(64), 0, stream>>>(
      sup, cols, vals, cnt, gc_b, out);
}

// Round 6
// 302.780 us; speedup vs baseline: 1.1921x; 1.1921x over previous
//
#include <hip/hip_runtime.h>
#include <math.h>

#define N      6144
#define NFEAT  128
#define HID    128
#define NHEADS 8
#define NCLASS 40
#define NCPAD  48        // NCLASS padded to 3 MFMA n-tiles
#define CAP    96        // ELL capacity per row; mean degree ~13
#define EPS    1e-5f
#define ALPHA  0.2f

typedef short bf16x8 __attribute__((ext_vector_type(8)));
typedef float f32x4  __attribute__((ext_vector_type(4)));

__device__ inline float bf2f(unsigned short u) {
  unsigned int x = ((unsigned int)u) << 16;
  return __builtin_bit_cast(float, x);
}
__device__ inline unsigned short f2bf(float f) {
  unsigned int x = __builtin_bit_cast(unsigned int, f);
  x += 0x7fffu + ((x >> 16) & 1u);          // round-to-nearest-even
  return (unsigned short)(x >> 16);
}

// ------- fused: ELL build (blocks 0..N-1) + BN0/W/gcw prep (blocks N..) ---
__global__ __launch_bounds__(256) void prep_ell_kernel(
    const float* __restrict__ adj,
    int* __restrict__ cols, float* __restrict__ vals, int* __restrict__ cnt,
    const float* __restrict__ x,
    const float* __restrict__ g, const float* __restrict__ b,
    const float* __restrict__ m, const float* __restrict__ v,
    const float* __restrict__ Wall, const float* __restrict__ gcw,
    unsigned short* __restrict__ xb, unsigned short* __restrict__ wbt,
    unsigned short* __restrict__ gctb) {
  __shared__ int scnt;
  if (blockIdx.x < N) {
    const int i = blockIdx.x;
    if (threadIdx.x == 0) scnt = 0;
    __syncthreads();
    const float* row = adj + (size_t)i * N;
    for (int j4 = threadIdx.x * 4; j4 < N; j4 += 1024) {
      float4 a = *(const float4*)(row + j4);
#pragma unroll
      for (int u = 0; u < 4; ++u) {
        float av = (u == 0) ? a.x : (u == 1) ? a.y : (u == 2) ? a.z : a.w;
        if (av > 0.f) {
          int s = atomicAdd(&scnt, 1);
          if (s < CAP) {
            cols[(size_t)i * CAP + s] = j4 + u;
            vals[(size_t)i * CAP + s] = av;
          }
        }
      }
    }
    __syncthreads();
    if (threadIdx.x == 0) cnt[i] = min(scnt, CAP);
  } else {
    int idx = (blockIdx.x - N) * 256 + threadIdx.x;
    if (idx < N * NFEAT) {
      int c = idx & (NFEAT - 1);
      float sc = g[c] * rsqrtf(v[c] + EPS);
      xb[idx] = f2bf((x[idx] - m[c]) * sc + b[c]);
    } else if (idx < N * NFEAT + NHEADS * NFEAT * HID) {
      int t = idx - N * NFEAT;            // t indexes wbt [h][n][k]
      int h = t >> 14, nk = t & 16383, n = nk >> 7, k = nk & 127;
      wbt[t] = f2bf(Wall[(h << 14) + (k << 7) + n]);
    } else {
      int t = idx - N * NFEAT - NHEADS * NFEAT * HID;  // gctb [NCPAD][1024]
      int cls = t >> 10, k = t & 1023;
      gctb[t] = (cls < NCLASS) ? f2bf(gcw[k * NCLASS + cls]) : (unsigned short)0;
    }
  }
}

// ------- GEMM (bf16 MFMA, LDS-staged) + fused score epilogue --------------
__global__ __launch_bounds__(256) void gemm_score(
    const unsigned short* __restrict__ xb,   // [N][128] bf16
    const unsigned short* __restrict__ wbt,  // [h][n][k] bf16 (W^T per head)
    const float* __restrict__ a_src, const float* __restrict__ a_dst,
    unsigned short* __restrict__ whc,        // [N][NHEADS*HID] bf16
    float* __restrict__ s1, float* __restrict__ s2) {
  const int h  = blockIdx.y;
  const int rb = blockIdx.x * 64;
  __shared__ unsigned short As[64][136];     // +8 pad: 16B-aligned, 2-way free
  __shared__ unsigned short Bs[128][136];
  __shared__ float s1p[64], s2p[64];
  const int tid = threadIdx.x;

  if (tid < 64) { s1p[tid] = 0.f; s2p[tid] = 0.f; }
#pragma unroll
  for (int r = 0; r < 4; ++r) {              // stage A: 64x128, coalesced
    int chunk = tid + r * 256;
    int row = chunk >> 4, c8 = (chunk & 15) * 8;
    *(uint4*)&As[row][c8] = *(const uint4*)(xb + (size_t)(rb + row) * NFEAT + c8);
  }
  const unsigned short* W = wbt + h * (HID * NFEAT);
#pragma unroll
  for (int r = 0; r < 8; ++r) {              // stage B: 128x128, coalesced
    int chunk = tid + r * 256;
    int row = chunk >> 4, c8 = (chunk & 15) * 8;
    *(uint4*)&Bs[row][c8] = *(const uint4*)(W + (size_t)row * NFEAT + c8);
  }
  __syncthreads();

  const int wid = tid >> 6, l = tid & 63, lm = l & 15, lq = l >> 4;
  const int cw = wid * 32;
  f32x4 acc[4][2] = {};
#pragma unroll
  for (int kk = 0; kk < NFEAT; kk += 32) {
    bf16x8 af[4], bfr[2];
#pragma unroll
    for (int mt = 0; mt < 4; ++mt)
      af[mt] = *(const bf16x8*)&As[mt * 16 + lm][kk + lq * 8];
#pragma unroll
    for (int nt = 0; nt < 2; ++nt)
      bfr[nt] = *(const bf16x8*)&Bs[cw + nt * 16 + lm][kk + lq * 8];
#pragma unroll
    for (int mt = 0; mt < 4; ++mt)
#pragma unroll
      for (int nt = 0; nt < 2; ++nt)
        acc[mt][nt] = __builtin_amdgcn_mfma_f32_16x16x32_bf16(
            af[mt], bfr[nt], acc[mt][nt], 0, 0, 0);
  }

  unsigned short* C = whc + (size_t)h * HID;
#pragma unroll
  for (int mt = 0; mt < 4; ++mt)
#pragma unroll
    for (int nt = 0; nt < 2; ++nt)
#pragma unroll
      for (int r = 0; r < 4; ++r)
        C[(size_t)(rb + mt * 16 + lq * 4 + r) * (NHEADS * HID)
          + cw + nt * 16 + lm] = f2bf(acc[mt][nt][r]);

  const float as0 = a_src[h * HID + cw + lm];
  const float as1 = a_src[h * HID + cw + 16 + lm];
  const float ad0 = a_dst[h * HID + cw + lm];
  const float ad1 = a_dst[h * HID + cw + 16 + lm];
#pragma unroll
  for (int mt = 0; mt < 4; ++mt)
#pragma unroll
    for (int r = 0; r < 4; ++r) {
      float p1 = acc[mt][0][r] * as0 + acc[mt][1][r] * as1;
      float p2 = acc[mt][0][r] * ad0 + acc[mt][1][r] * ad1;
#pragma unroll
      for (int off = 1; off < 16; off <<= 1) {
        p1 += __shfl_xor(p1, off, 64);
        p2 += __shfl_xor(p2, off, 64);
      }
      if (lm == 0) {
        atomicAdd(&s1p[mt * 16 + lq * 4 + r], p1);
        atomicAdd(&s2p[mt * 16 + lq * 4 + r], p2);
      }
    }
  __syncthreads();
  if (tid < 64) {
    s1[(size_t)h * N + rb + tid] = s1p[tid];
    s2[(size_t)h * N + rb + tid] = s2p[tid];
  }
}

// ------- attention: one block per row, all 8 heads; bf16 xcat out ---------
__global__ __launch_bounds__(256) void attn_kernel(
    const unsigned short* __restrict__ whc,  // [N][1024]
    const float* __restrict__ s1, const float* __restrict__ s2,
    const int* __restrict__ cols, const int* __restrict__ cnt,
    const float* __restrict__ g, const float* __restrict__ b,
    const float* __restrict__ m, const float* __restrict__ v,
    unsigned short* __restrict__ xcatb) {    // [N][1024] bf16
  const int i = blockIdx.x, t = threadIdx.x;
  __shared__ int   jsh[CAP + 2];
  __shared__ float wsh[NHEADS][CAP + 2];
  __shared__ float ssum[NHEADS];
  __shared__ float accsh[128][9];

  const int c = cnt[i];
  const int cpad = (c + 1) & ~1;
  if (t < CAP + 2) jsh[t] = (t < c) ? cols[(size_t)i * CAP + t] : 0;
  if (t < 16) wsh[t >> 1][c + (t & 1)] = 0.f;    // zero 2-pad for all heads
  __syncthreads();

  if (t < 128) {                       // 16 threads per head
    const int h = t >> 4, u = t & 15;
    const float si = s1[(size_t)h * N + i];
    const float* s2h = s2 + (size_t)h * N;
    float mx = -INFINITY;
    for (int e = u; e < c; e += 16) {
      float val = si + s2h[jsh[e]];
      val = val >= 0.f ? val : ALPHA * val;
      mx = fmaxf(mx, val);
    }
#pragma unroll
    for (int off = 1; off < 16; off <<= 1) mx = fmaxf(mx, __shfl_xor(mx, off, 64));
    float sm = 0.f;
    for (int e = u; e < c; e += 16) {
      float val = si + s2h[jsh[e]];
      val = val >= 0.f ? val : ALPHA * val;
      float wv = expf(val - mx);
      wsh[h][e] = wv;
      sm += wv;
    }
#pragma unroll
    for (int off = 1; off < 16; off <<= 1) sm += __shfl_xor(sm, off, 64);
    if (u == 0) ssum[h] = sm;
  }
  __syncthreads();

  const int p  = t >> 7;               // edge parity
  const int q  = t & 127;              // feature block: feats 8q..8q+7
  const int f0 = q * 8;
  const int hh = q >> 4;               // head of this feature block
  float acc[8] = {0.f, 0.f, 0.f, 0.f, 0.f, 0.f, 0.f, 0.f};
  for (int e = 0; e < cpad; e += 2) {
    const int   j = jsh[e + p];
    const float w = wsh[hh][e + p];
    uint4 U = *(const uint4*)(whc + (size_t)j * (NHEADS * HID) + f0);
    acc[0] += w * bf2f((unsigned short)(U.x & 0xffff));
    acc[1] += w * bf2f((unsigned short)(U.x >> 16));
    acc[2] += w * bf2f((unsigned short)(U.y & 0xffff));
    acc[3] += w * bf2f((unsigned short)(U.y >> 16));
    acc[4] += w * bf2f((unsigned short)(U.z & 0xffff));
    acc[5] += w * bf2f((unsigned short)(U.z >> 16));
    acc[6] += w * bf2f((unsigned short)(U.w & 0xffff));
    acc[7] += w * bf2f((unsigned short)(U.w >> 16));
  }
  if (p == 1) {
#pragma unroll
    for (int j = 0; j < 8; ++j) accsh[q][j] = acc[j];
  }
  __syncthreads();
  if (p == 0) {
    const float inv = 1.f / ssum[hh];
    const int ch0 = (q & 15) * 8;      // BN channel base within head
    float4 gv0 = *(const float4*)(g + ch0), gv1 = *(const float4*)(g + ch0 + 4);
    float4 bv0 = *(const float4*)(b + ch0), bv1 = *(const float4*)(b + ch0 + 4);
    float4 mv0 = *(const float4*)(m + ch0), mv1 = *(const float4*)(m + ch0 + 4);
    float4 vv0 = *(const float4*)(v + ch0), vv1 = *(const float4*)(v + ch0 + 4);
    float gg[8] = {gv0.x, gv0.y, gv0.z, gv0.w, gv1.x, gv1.y, gv1.z, gv1.w};
    float bb[8] = {bv0.x, bv0.y, bv0.z, bv0.w, bv1.x, bv1.y, bv1.z, bv1.w};
    float mm[8] = {mv0.x, mv0.y, mv0.z, mv0.w, mv1.x, mv1.y, mv1.z, mv1.w};
    float vv[8] = {vv0.x, vv0.y, vv0.z, vv0.w, vv1.x, vv1.y, vv1.z, vv1.w};
    unsigned short ob[8];
#pragma unroll
    for (int j = 0; j < 8; ++j) {
      float hp = (acc[j] + accsh[q][j]) * inv;
      ob[j] = f2bf(fmaxf((hp - mm[j]) * (gg[j] * rsqrtf(vv[j] + EPS)) + bb[j], 0.f));
    }
    uint4 U;
    U.x = (unsigned int)ob[0] | ((unsigned int)ob[1] << 16);
    U.y = (unsigned int)ob[2] | ((unsigned int)ob[3] << 16);
    U.z = (unsigned int)ob[4] | ((unsigned int)ob[5] << 16);
    U.w = (unsigned int)ob[6] | ((unsigned int)ob[7] << 16);
    *(uint4*)(xcatb + (size_t)i * (NHEADS * HID) + f0) = U;
  }
}

// ------- support = xcatb @ gcw via bf16 MFMA; wave = 16 rows --------------
__global__ __launch_bounds__(256) void support_mfma(
    const unsigned short* __restrict__ xcatb,  // [N][1024] bf16
    const unsigned short* __restrict__ gctb,   // [NCPAD][1024] bf16 (gcw^T)
    float* __restrict__ sup) {                 // [N][NCLASS] fp32
  const int wv = (blockIdx.x * 256 + threadIdx.x) >> 6;   // 0..383
  const int l = threadIdx.x & 63, lm = l & 15, lq = l >> 4;
  const int rb = wv * 16;
  f32x4 acc[3] = {};
  for (int kk = 0; kk < NHEADS * HID; kk += 32) {
    bf16x8 a = *(const bf16x8*)(xcatb + (size_t)(rb + lm) * (NHEADS * HID) + kk + lq * 8);
#pragma unroll
    for (int nt = 0; nt < 3; ++nt) {
      bf16x8 bb = *(const bf16x8*)(gctb + (size_t)(nt * 16 + lm) * (NHEADS * HID) + kk + lq * 8);
      acc[nt] = __builtin_amdgcn_mfma_f32_16x16x32_bf16(a, bb, acc[nt], 0, 0, 0);
    }
  }
#pragma unroll
  for (int nt = 0; nt < 3; ++nt)
#pragma unroll
    for (int r = 0; r < 4; ++r) {
      int col = nt * 16 + lm;
      if (col < NCLASS)
        sup[(size_t)(rb + lq * 4 + r) * NCLASS + col] = acc[nt][r];
    }
}

// --------- out = log_softmax((0.5*A@sup + sup)/1.5 + gc_b), wave per row -
__global__ __launch_bounds__(64) void final_kernel(
    const float* __restrict__ sup,
    const int* __restrict__ cols, const float* __restrict__ vals,
    const int* __restrict__ cnt, const float* __restrict__ gcb,
    float* __restrict__ out) {
  const int i = blockIdx.x, t = threadIdx.x;
  const bool act = t < NCLASS;
  const int c = cnt[i];
  const int* cl = cols + (size_t)i * CAP;
  const float* vl = vals + (size_t)i * CAP;
  float s = act ? sup[(size_t)i * NCLASS + t] : 0.f;
  float agg = 0.f;
  for (int e = 0; e < c; ++e) {
    int j = cl[e];
    float a = vl[e];
    if (act) agg += a * sup[(size_t)j * NCLASS + t];
  }
  float o = act ? ((0.5f * agg + s) * (1.f / 1.5f) + gcb[t]) : -INFINITY;
  float mx = o;
#pragma unroll
  for (int off = 32; off; off >>= 1) mx = fmaxf(mx, __shfl_xor(mx, off, 64));
  float ex = act ? expf(o - mx) : 0.f;
#pragma unroll
  for (int off = 32; off; off >>= 1) ex += __shfl_xor(ex, off, 64);
  if (act) out[(size_t)i * NCLASS + t] = o - mx - logf(ex);
}

// -------------------------------------------------------------------------
extern "C" void kernel_launch(void* const* d_in, const int* in_sizes, int n_in,
                              void* d_out, int out_size, void* d_ws, size_t ws_size,
                              hipStream_t stream) {
  const float* x     = (const float*)d_in[0];
  const float* adj   = (const float*)d_in[1];
  const float* W_att = (const float*)d_in[2];
  const float* a_src = (const float*)d_in[3];
  const float* a_dst = (const float*)d_in[4];
  const float* bn0_g = (const float*)d_in[5];
  const float* bn0_b = (const float*)d_in[6];
  const float* bn0_m = (const float*)d_in[7];
  const float* bn0_v = (const float*)d_in[8];
  const float* bn1_g = (const float*)d_in[9];
  const float* bn1_b = (const float*)d_in[10];
  const float* bn1_m = (const float*)d_in[11];
  const float* bn1_v = (const float*)d_in[12];
  const float* gc_w  = (const float*)d_in[13];
  const float* gc_b  = (const float*)d_in[14];
  float* out = (float*)d_out;
  (void)in_sizes; (void)n_in; (void)out_size; (void)ws_size;

  char* w = (char*)d_ws;
  unsigned short* xb    = (unsigned short*)w; w += (size_t)N * NFEAT * 2;
  unsigned short* wbt   = (unsigned short*)w; w += (size_t)NHEADS * NFEAT * HID * 2;
  unsigned short* whc   = (unsigned short*)w; w += (size_t)N * NHEADS * HID * 2;
  unsigned short* xcatb = (unsigned short*)w; w += (size_t)N * NHEADS * HID * 2;
  unsigned short* gctb  = (unsigned short*)w; w += (size_t)NCPAD * NHEADS * HID * 2;
  float* s1   = (float*)w; w += (size_t)NHEADS * N * 4;
  float* s2   = (float*)w; w += (size_t)NHEADS * N * 4;
  float* sup  = (float*)w; w += (size_t)N * NCLASS * 4;
  float* vals = (float*)w; w += (size_t)N * CAP * 4;
  int*   cols = (int*)w;   w += (size_t)N * CAP * 4;
  int*   cnt  = (int*)w;   w += (size_t)N * 4;

  // prep blocks: xb (3072) + wbt (512) + gctb (192) = 3776
  const int prep_blocks =
      (N * NFEAT + NHEADS * NFEAT * HID + NCPAD * NHEADS * HID) / 256;
  prep_ell_kernel<<<dim3(N + prep_blocks), dim3(256), 0, stream>>>(
      adj, cols, vals, cnt, x, bn0_g, bn0_b, bn0_m, bn0_v, W_att, gc_w,
      xb, wbt, gctb);
  gemm_score<<<dim3(N / 64, NHEADS), dim3(256), 0, stream>>>(
      xb, wbt, a_src, a_dst, whc, s1, s2);
  attn_kernel<<<dim3(N), dim3(256), 0, stream>>>(
      whc, s1, s2, cols, cnt, bn1_g, bn1_b, bn1_m, bn1_v, xcatb);
  support_mfma<<<dim3(N / 16 / 4), dim3(256), 0, stream>>>(
      xcatb, gctb, sup);
  final_kernel<<<dim3(N), dim3(64), 0, stream>>>(
      sup, cols, vals, cnt, gc_b, out);
}